// Round 1
// 306.655 us; speedup vs baseline: 1.0118x; 1.0118x over previous
//
#include <hip/hip_runtime.h>
#include <hip/hip_bf16.h>

// Split pipeline: (1) prep planes via LDS transpose (coalesced both sides),
// (2) sample_k: triplane bilinear sample -> bf16 features in g_feat, high
// occupancy (no LDS, low VGPR), (3) mlp_k: MFMA MLP reading g_feat with the
// byte-identical [wg][c][nl] layout the fused kernel used, targeted lgkmcnt
// waits instead of full s_waitcnt(0) drains, and a-fragment prefetch.

#define C_ 32
#define HW_ (128 * 128)
#define NPTS (4 * 262144)
#define HBS 136               /* per-wave transpose buf row stride (bf16) */

typedef short s8v __attribute__((ext_vector_type(8)));
typedef float f4v __attribute__((ext_vector_type(4)));
typedef unsigned int u4v __attribute__((ext_vector_type(4)));

__device__ __attribute__((aligned(64))) unsigned short g_planes[3 * HW_ * C_]; // (3,H,W,C) bf16
__device__ __attribute__((aligned(64))) unsigned short g_feat[NPTS * C_];      // [wg][c][nl] bf16, 64 MB
__device__ __attribute__((aligned(16))) unsigned short g_w0[128 * 32];
__device__ __attribute__((aligned(16))) unsigned short g_w1[128 * 128];
__device__ __attribute__((aligned(16))) unsigned short g_w2[16 * 128];  // perm-baked, padded
__device__ float g_b0[128];
__device__ float g_b1[128];
__device__ float g_b2p[16];

template <typename TO, typename FROM>
static __device__ __forceinline__ TO bitc(FROM f) {
    union { FROM a; TO b; } u; u.a = f; return u.b;
}

// MFMA operand-type shim (v8i16 vs v8bf16 builtin signature) -- proven.
template <typename V>
static __device__ __forceinline__ auto mfma_k32(V a, V b, f4v c, int)
    -> decltype(__builtin_amdgcn_mfma_f32_16x16x32_bf16(a, b, c, 0, 0, 0)) {
    return __builtin_amdgcn_mfma_f32_16x16x32_bf16(a, b, c, 0, 0, 0);
}
template <typename V>
static __device__ __forceinline__ f4v mfma_k32(V a, V b, f4v c, long) {
    typedef __bf16 b8v __attribute__((ext_vector_type(8)));
    return __builtin_amdgcn_mfma_f32_16x16x32_bf16(bitc<b8v>(a), bitc<b8v>(b), c, 0, 0, 0);
}
static __device__ __forceinline__ f4v MFMA(s8v a, s8v b, f4v c) {
    return mfma_k32(a, b, c, 0);
}

__device__ __forceinline__ unsigned short f2bf(float f) {
    union { float f; unsigned int i; } v; v.f = f;
    unsigned int r = v.i + 0x7FFFu + ((v.i >> 16) & 1u);
    return (unsigned short)(r >> 16);
}

#define LGKM0() do { asm volatile("s_waitcnt lgkmcnt(0)" ::: "memory"); \
                     __builtin_amdgcn_sched_barrier(0); } while (0)

// ---- prep: planes (3C,H,W) fp32 -> (3,H,W,C) bf16, LDS tile transpose ------
__global__ __launch_bounds__(256) void prep_planes_k(const float* __restrict__ tp) {
    __shared__ float buf[32][65];
    const int tid = threadIdx.x;
    const int bid = blockIdx.x;          // 0..767
    const int pl  = bid >> 8;            // plane 0..2
    const int xy0 = (bid & 255) << 6;    // 64-texel chunk
#pragma unroll
    for (int i = 0; i < 8; ++i) {
        int idx = i * 256 + tid;
        int c = idx >> 6, x = idx & 63;                       // coalesced read
        buf[c][x] = tp[(pl * C_ + c) * HW_ + xy0 + x];
    }
    __syncthreads();
#pragma unroll
    for (int i = 0; i < 8; ++i) {
        int idx = i * 256 + tid;
        int x = idx >> 5, c = idx & 31;                       // coalesced write
        g_planes[(pl * HW_ + xy0 + x) * C_ + c] = f2bf(buf[c][x]);
    }
}

// ---- prep: weights/biases -> bf16; w2/b2 permuted [1,2,3,0], padded ---------
__global__ void prep_weights_k(const float* __restrict__ w0, const float* __restrict__ b0,
                               const float* __restrict__ w1, const float* __restrict__ b1,
                               const float* __restrict__ w2, const float* __restrict__ b2) {
    int i = blockIdx.x * 256 + threadIdx.x;   // 16384 threads
    if (i < 128 * 32)  g_w0[i] = f2bf(w0[i]);
    if (i < 128 * 128) g_w1[i] = f2bf(w1[i]);
    if (i < 16 * 128) {
        int n = i >> 7, k = i & 127;
        g_w2[i] = f2bf(n < 4 ? w2[((n + 1) & 3) * 128 + k] : 0.0f);
    }
    if (i < 128) { g_b0[i] = b0[i]; g_b1[i] = b1[i]; }
    if (i < 16)  g_b2p[i] = (i < 4) ? b2[(i + 1) & 3] : 0.0f;
}

// ---- bilinear sample: all 32 channels via 16B vector loads ------------------
__device__ __forceinline__ void sample_plane32(const unsigned short* __restrict__ pbase,
                                               float u, float v, float* facc) {
    float x = (u + 1.0f) * 63.5f;             // align_corners=True, W=H=128
    float y = (v + 1.0f) * 63.5f;
    float xf = floorf(x), yf = floorf(y);
    float wx = x - xf, wy = y - yf;
    int x0 = (int)xf, y0 = (int)yf;
#pragma unroll
    for (int dy = 0; dy < 2; ++dy) {
        int yi = y0 + dy;
        float wyv = dy ? wy : 1.0f - wy;
        bool vy = (yi >= 0) && (yi < 128);
        int yc = yi < 0 ? 0 : (yi > 127 ? 127 : yi);
#pragma unroll
        for (int dx = 0; dx < 2; ++dx) {
            int xi = x0 + dx;
            float wv = (dx ? wx : 1.0f - wx) * wyv;
            bool vx = (xi >= 0) && (xi < 128);
            int xc = xi < 0 ? 0 : (xi > 127 ? 127 : xi);
            wv = (vx && vy) ? wv : 0.0f;
            const u4v* cp = (const u4v*)(pbase + (yc * 128 + xc) * C_);
#pragma unroll
            for (int q = 0; q < 4; ++q) {
                u4v dw = cp[q];
#pragma unroll
                for (int jj = 0; jj < 4; ++jj) {
                    facc[q * 8 + 2 * jj]     += wv * __uint_as_float(dw[jj] << 16);
                    facc[q * 8 + 2 * jj + 1] += wv * __uint_as_float(dw[jj] & 0xFFFF0000u);
                }
            }
        }
    }
}

// ---- kernel 1: sample 512 points/block -> g_feat[wg][c][nl] -----------------
__global__ __launch_bounds__(256) void sample_k(const float* __restrict__ coords) {
    const int tid = threadIdx.x;
    const int wg  = blockIdx.x;               // 0..2047
    const int b   = wg >> 9;
    const int nb  = wg & 511;
    const int n0  = nb << 9;
    unsigned short* fb = g_feat + (size_t)wg * 16384;
#pragma unroll 1
    for (int pt = 0; pt < 2; ++pt) {
        const int nl = tid + pt * 256;        // n_local 0..511
        const float* cp = coords + (size_t)(b * 262144 + n0 + nl) * 3;
        const float gx = cp[0], gy = cp[1], gz = cp[2];
        float facc[32];
#pragma unroll
        for (int c = 0; c < 32; ++c) facc[c] = 0.0f;
        sample_plane32(g_planes + 0 * (HW_ * C_), gx, gy, facc);  // feat_xy
        sample_plane32(g_planes + 2 * (HW_ * C_), gx, gz, facc);  // feat_xz
        sample_plane32(g_planes + 1 * (HW_ * C_), gy, gz, facc);  // feat_yz
#pragma unroll
        for (int c = 0; c < 32; ++c)
            fb[c * 512 + nl] = f2bf(facc[c]);                     // coalesced 2B/lane
    }
}

// ---- kernel 2: MFMA MLP, 32 tiles/block (8 per wave) ------------------------
__global__ __launch_bounds__(256) void mlp_k(float* __restrict__ out) {
    __shared__ __attribute__((aligned(16))) unsigned short tb[4 * 16 * HBS];
    const int tid  = threadIdx.x;
    const int wave = tid >> 6;
    const int lane = tid & 63;
    const int l15  = lane & 15;
    const int quad = lane >> 4;
    const int ch8  = quad * 8;

    const int wg = blockIdx.x;                // 0..2047
    const int b  = wg >> 9;
    const int nb = wg & 511;
    const unsigned short* fb = g_feat + (size_t)wg * 16384;

    // ---- weight fragments (verbatim from proven kernel) ---------------------
    s8v w0f[8], w1f[4][8], w2f[4];
#pragma unroll
    for (int nt = 0; nt < 8; ++nt)
        w0f[nt] = *(const s8v*)(g_w0 + (nt * 16 + l15) * 32 + ch8);
#pragma unroll
    for (int kc = 0; kc < 4; ++kc)
#pragma unroll
        for (int nt = 0; nt < 8; ++nt)
            w1f[kc][nt] = *(const s8v*)(g_w1 + (nt * 16 + l15) * 128 + kc * 32 + ch8);
#pragma unroll
    for (int kc = 0; kc < 4; ++kc)
        w2f[kc] = *(const s8v*)(g_w2 + l15 * 128 + kc * 32 + ch8);
    float bias0[8], bias1[8];
#pragma unroll
    for (int nt = 0; nt < 8; ++nt) {
        bias0[nt] = g_b0[nt * 16 + l15];
        bias1[nt] = g_b1[nt * 16 + l15];
    }
    const float bias2 = g_b2p[l15];

    unsigned short* hb = tb + wave * (16 * HBS);  // per-wave private
    float* hbf = (float*)hb;

    // prefetch first A fragment
    s8v a_cur = *(const s8v*)(fb + (wave * 8) * 512 + l15 * 32 + ch8);

#pragma unroll 1
    for (int i = 0; i < 8; ++i) {
        const int ci = wave * 8 + i;          // tile 0..31
        const s8v a = a_cur;
        if (i < 7)                            // issue next tile's load early
            a_cur = *(const s8v*)(fb + (ci + 1) * 512 + l15 * 32 + ch8);

        // layer 1: one nt at a time (keeps acc live-range at 1 f4v)
#pragma unroll
        for (int nt = 0; nt < 8; ++nt) {
            f4v bi;
            bi[0] = bias0[nt]; bi[1] = bias0[nt]; bi[2] = bias0[nt]; bi[3] = bias0[nt];
            f4v c1 = MFMA(a, w0f[nt], bi);
#pragma unroll
            for (int r = 0; r < 4; ++r) {
                float v = c1[r];
                hb[(quad * 4 + r) * HBS + nt * 16 + l15] = f2bf(v > 0.0f ? v : 0.0f);
            }
        }
        LGKM0();
        s8v a2[4];
#pragma unroll
        for (int kc = 0; kc < 4; ++kc)
            a2[kc] = *(const s8v*)(hb + l15 * HBS + kc * 32 + ch8);

        // layer 2 in two nt-halves (d live-range 4 f4v)
#pragma unroll
        for (int half = 0; half < 2; ++half) {
            f4v d[4];
#pragma unroll
            for (int j = 0; j < 4; ++j) {
                float bv = bias1[half * 4 + j];
                d[j][0] = bv; d[j][1] = bv; d[j][2] = bv; d[j][3] = bv;
            }
#pragma unroll
            for (int kc = 0; kc < 4; ++kc)
#pragma unroll
                for (int j = 0; j < 4; ++j)
                    d[j] = MFMA(a2[kc], w1f[kc][half * 4 + j], d[j]);
#pragma unroll
            for (int j = 0; j < 4; ++j)
#pragma unroll
                for (int r = 0; r < 4; ++r) {
                    float v = d[j][r];
                    hb[(quad * 4 + r) * HBS + (half * 4 + j) * 16 + l15] =
                        f2bf(v > 0.0f ? v : 0.0f);
                }
        }
        LGKM0();
        s8v a3[4];
#pragma unroll
        for (int kc = 0; kc < 4; ++kc)
            a3[kc] = *(const s8v*)(hb + l15 * HBS + kc * 32 + ch8);

        // layer 3 -> relu; C layout: row=quad*4+r, col=l15 (cols 0..3 valid)
        f4v o;
        o[0] = bias2; o[1] = bias2; o[2] = bias2; o[3] = bias2;
#pragma unroll
        for (int kc = 0; kc < 4; ++kc)
            o = MFMA(a3[kc], w2f[kc], o);

        // transpose 16x4 through LDS -> one coalesced 256B store per tile
        if (l15 < 4) {
#pragma unroll
            for (int r = 0; r < 4; ++r) {
                float v = o[r];
                hbf[(quad * 4 + r) * 4 + l15] = v > 0.0f ? v : 0.0f;
            }
        }
        LGKM0();
        const int t = b * 16384 + ci * 512 + nb;   // global tile index
        if (lane < 16) {
            f4v row = *(const f4v*)(hbf + lane * 4);
            *(f4v*)(out + (size_t)(t * 16 + lane) * 4) = row;
        }
        LGKM0();                              // hbf reads done before next tile
    }
}

extern "C" void kernel_launch(void* const* d_in, const int* in_sizes, int n_in,
                              void* d_out, int out_size, void* d_ws, size_t ws_size,
                              hipStream_t stream) {
    const float* coords = (const float*)d_in[0];
    const float* tp = (const float*)d_in[1];
    const float* w0 = (const float*)d_in[2];
    const float* b0 = (const float*)d_in[3];
    const float* w1 = (const float*)d_in[4];
    const float* b1 = (const float*)d_in[5];
    const float* w2 = (const float*)d_in[6];
    const float* b2 = (const float*)d_in[7];
    float* out = (float*)d_out;               // FP32 output

    prep_planes_k<<<768, 256, 0, stream>>>(tp);
    prep_weights_k<<<64, 256, 0, stream>>>(w0, b0, w1, b1, w2, b2);
    sample_k<<<2048, 256, 0, stream>>>(coords);
    mlp_k<<<2048, 256, 0, stream>>>(out);
}

// Round 3
// 219.123 us; speedup vs baseline: 1.4160x; 1.3995x over previous
//
#include <hip/hip_runtime.h>
#include <hip/hip_bf16.h>

// Fused triplane sample + MLP (32->128->128->4, ReLU), perm [1,2,3,0] baked.
// Phase B uses OPERAND-SWAPPED MFMAs: MFMA(w, x) gives the transposed C tile
// in-place, so inter-layer transposes become packed ds_write_b64 (cvt_pk
// pairs) instead of 4x scalar ds_write_b16 + manual f2bf, and layer-3 output
// stores directly from registers (quad 0 holds all 4 comps of its point).
// Biases enter as MFMA C-init via small LDS table reads (laundered vs LICM).

#define C_ 32
#define HW_ (128 * 128)
#define HBS2 136              /* hb row stride in bf16: 16 rows x 128 ch (+8 pad) */

typedef short s8v __attribute__((ext_vector_type(8)));
typedef float f4v __attribute__((ext_vector_type(4)));
typedef unsigned int u4v __attribute__((ext_vector_type(4)));
typedef unsigned int u2v __attribute__((ext_vector_type(2)));

__device__ __attribute__((aligned(64))) unsigned short g_planes[3 * HW_ * C_]; // (3,H,W,C) bf16
__device__ __attribute__((aligned(16))) unsigned short g_w0[128 * 32];
__device__ __attribute__((aligned(16))) unsigned short g_w1[128 * 128];
__device__ __attribute__((aligned(16))) unsigned short g_w2[16 * 128];  // perm-baked, padded
__device__ __attribute__((aligned(16))) float g_b0[128];
__device__ __attribute__((aligned(16))) float g_b1[128];
__device__ __attribute__((aligned(16))) float g_b2p[16];

template <typename TO, typename FROM>
static __device__ __forceinline__ TO bitc(FROM f) {
    union { FROM a; TO b; } u; u.a = f; return u.b;
}

// MFMA operand-type shim (v8i16 vs v8bf16 builtin signature) -- proven.
template <typename V>
static __device__ __forceinline__ auto mfma_k32(V a, V b, f4v c, int)
    -> decltype(__builtin_amdgcn_mfma_f32_16x16x32_bf16(a, b, c, 0, 0, 0)) {
    return __builtin_amdgcn_mfma_f32_16x16x32_bf16(a, b, c, 0, 0, 0);
}
template <typename V>
static __device__ __forceinline__ f4v mfma_k32(V a, V b, f4v c, long) {
    typedef __bf16 b8v __attribute__((ext_vector_type(8)));
    return __builtin_amdgcn_mfma_f32_16x16x32_bf16(bitc<b8v>(a), bitc<b8v>(b), c, 0, 0, 0);
}
static __device__ __forceinline__ f4v MFMA(s8v a, s8v b, f4v c) {
    return mfma_k32(a, b, c, 0);
}

__device__ __forceinline__ unsigned short f2bf(float f) {
    union { float f; unsigned int i; } v; v.f = f;
    unsigned int r = v.i + 0x7FFFu + ((v.i >> 16) & 1u);
    return (unsigned short)(r >> 16);
}

// relu + pack 2 floats -> 1 u32 of 2 bf16 via v_cvt_pk_bf16_f32 (no builtin
// on gfx950 -- inline asm per guide T12; pure asm, scheduler may move it)
static __device__ __forceinline__ unsigned int relu_pk(float a, float b) {
    float x = a > 0.0f ? a : 0.0f;
    float y = b > 0.0f ? b : 0.0f;
    unsigned int r;
    asm("v_cvt_pk_bf16_f32 %0, %1, %2" : "=v"(r) : "v"(x), "v"(y));
    return r;
}

#define LGKM0() do { asm volatile("s_waitcnt lgkmcnt(0)" ::: "memory"); \
                     __builtin_amdgcn_sched_barrier(0); } while (0)

// ---- prep: planes (3C,H,W) fp32 -> (3,H,W,C) bf16, LDS tile transpose ------
__global__ __launch_bounds__(256) void prep_planes_k(const float* __restrict__ tp) {
    __shared__ float buf[32][65];
    const int tid = threadIdx.x;
    const int bid = blockIdx.x;          // 0..767
    const int pl  = bid >> 8;            // plane 0..2
    const int xy0 = (bid & 255) << 6;    // 64-texel chunk
#pragma unroll
    for (int i = 0; i < 8; ++i) {
        int idx = i * 256 + tid;
        int c = idx >> 6, x = idx & 63;                       // coalesced read
        buf[c][x] = tp[(pl * C_ + c) * HW_ + xy0 + x];
    }
    __syncthreads();
#pragma unroll
    for (int i = 0; i < 8; ++i) {
        int idx = i * 256 + tid;
        int x = idx >> 5, c = idx & 31;                       // coalesced write
        g_planes[(pl * HW_ + xy0 + x) * C_ + c] = f2bf(buf[c][x]);
    }
}

// ---- prep: weights/biases -> bf16; w2/b2 permuted [1,2,3,0], padded ---------
__global__ void prep_weights_k(const float* __restrict__ w0, const float* __restrict__ b0,
                               const float* __restrict__ w1, const float* __restrict__ b1,
                               const float* __restrict__ w2, const float* __restrict__ b2) {
    int i = blockIdx.x * 256 + threadIdx.x;   // 16384 threads
    if (i < 128 * 32)  g_w0[i] = f2bf(w0[i]);
    if (i < 128 * 128) g_w1[i] = f2bf(w1[i]);
    if (i < 16 * 128) {
        int n = i >> 7, k = i & 127;
        g_w2[i] = f2bf(n < 4 ? w2[((n + 1) & 3) * 128 + k] : 0.0f);
    }
    if (i < 128) { g_b0[i] = b0[i]; g_b1[i] = b1[i]; }
    if (i < 16)  g_b2p[i] = (i < 4) ? b2[(i + 1) & 3] : 0.0f;
}

// ---- bilinear sample: all 32 channels via 16B vector loads ------------------
__device__ __forceinline__ void sample_plane32(const unsigned short* __restrict__ pbase,
                                               float u, float v, float* facc) {
    float x = (u + 1.0f) * 63.5f;             // align_corners=True, W=H=128
    float y = (v + 1.0f) * 63.5f;
    float xf = floorf(x), yf = floorf(y);
    float wx = x - xf, wy = y - yf;
    int x0 = (int)xf, y0 = (int)yf;
#pragma unroll
    for (int dy = 0; dy < 2; ++dy) {
        int yi = y0 + dy;
        float wyv = dy ? wy : 1.0f - wy;
        bool vy = (yi >= 0) && (yi < 128);
        int yc = yi < 0 ? 0 : (yi > 127 ? 127 : yi);
#pragma unroll
        for (int dx = 0; dx < 2; ++dx) {
            int xi = x0 + dx;
            float wv = (dx ? wx : 1.0f - wx) * wyv;
            bool vx = (xi >= 0) && (xi < 128);
            int xc = xi < 0 ? 0 : (xi > 127 ? 127 : xi);
            wv = (vx && vy) ? wv : 0.0f;
            const u4v* cp = (const u4v*)(pbase + (yc * 128 + xc) * C_);
#pragma unroll
            for (int q = 0; q < 4; ++q) {
                u4v dw = cp[q];
#pragma unroll
                for (int jj = 0; jj < 4; ++jj) {
                    facc[q * 8 + 2 * jj]     += wv * __uint_as_float(dw[jj] << 16);
                    facc[q * 8 + 2 * jj + 1] += wv * __uint_as_float(dw[jj] & 0xFFFF0000u);
                }
            }
        }
    }
}

// ---- fused kernel -----------------------------------------------------------
__global__ __launch_bounds__(256) void fused_k(const float* __restrict__ coords,
                                               float* __restrict__ out) {
    // S[32][512] bf16 (32768 B) + 4 per-wave transpose bufs 16*HBS2 bf16.
    __shared__ __attribute__((aligned(16))) unsigned short smem[16384 + 4 * 16 * HBS2];
    __shared__ __attribute__((aligned(16))) float lds_bias[256];   // b0[128], b1[128]
    const int tid  = threadIdx.x;             // 0..255
    const int wave = tid >> 6;                // 0..3
    const int lane = tid & 63;
    const int l15  = lane & 15;
    const int quad = lane >> 4;
    const int ch8  = quad * 8;

    const int wg = blockIdx.x;                // 0..2047
    const int b  = wg >> 9;                   // batch
    const int nb = wg & 511;                  // 512-point block within batch
    const int n0 = nb << 9;

    if (tid < 128) { lds_bias[tid] = g_b0[tid]; lds_bias[128 + tid] = g_b1[tid]; }

    // ---- phase A: sample 2 points/thread, all 32 channels -> S --------------
#pragma unroll 1
    for (int pt = 0; pt < 2; ++pt) {
        const int nl = tid + pt * 256;        // n_local 0..511
        const float* cp = coords + (size_t)(b * 262144 + n0 + nl) * 3;
        const float gx = cp[0], gy = cp[1], gz = cp[2];
        float facc[32];
#pragma unroll
        for (int c = 0; c < 32; ++c) facc[c] = 0.0f;
        sample_plane32(g_planes + 0 * (HW_ * C_), gx, gy, facc);  // feat_xy
        sample_plane32(g_planes + 2 * (HW_ * C_), gx, gz, facc);  // feat_xz
        sample_plane32(g_planes + 1 * (HW_ * C_), gy, gz, facc);  // feat_yz
#pragma unroll
        for (int c = 0; c < 32; ++c)
            smem[c * 512 + nl] = f2bf(facc[c]);
    }
    __syncthreads();

    // ---- weight fragments (identical content to proven kernel) --------------
    s8v w0f[8], w1f[4][8], w2f[4];
#pragma unroll
    for (int nt = 0; nt < 8; ++nt)
        w0f[nt] = *(const s8v*)(g_w0 + (nt * 16 + l15) * 32 + ch8);
#pragma unroll
    for (int kc = 0; kc < 4; ++kc)
#pragma unroll
        for (int nt = 0; nt < 8; ++nt)
            w1f[kc][nt] = *(const s8v*)(g_w1 + (nt * 16 + l15) * 128 + kc * 32 + ch8);
#pragma unroll
    for (int kc = 0; kc < 4; ++kc)
        w2f[kc] = *(const s8v*)(g_w2 + l15 * 128 + kc * 32 + ch8);
    const f4v b2v = *(const f4v*)(g_b2p + quad * 4);   // swapped C-init, layer 3

    unsigned short* hb = smem + 16384 + wave * (16 * HBS2);  // per-wave private

    // ---- phase B: 8 tiles per wave, operand-swapped MFMAs -------------------
#pragma unroll 1
    for (int i = 0; i < 8; ++i) {
        const int ci = wave * 8 + i;          // tile 0..31
        int bo = 0;
        asm volatile("" : "+v"(bo));          // opaque 0: keep bias reads in-loop
        const float* bp = lds_bias + bo;

        const s8v a = *(const s8v*)(smem + ci * 512 + l15 * 32 + ch8);

        // layer 1 (swapped): position(q,l15,r) = C[l15][q*4+r] -> row-major write
#pragma unroll
        for (int nt = 0; nt < 8; ++nt) {
            const f4v bi = *(const f4v*)(bp + nt * 16 + quad * 4);
            f4v c1 = MFMA(w0f[nt], a, bi);
            u2v pk;
            pk[0] = relu_pk(c1[0], c1[1]);
            pk[1] = relu_pk(c1[2], c1[3]);
            *(u2v*)(hb + l15 * HBS2 + nt * 16 + quad * 4) = pk;
        }
        LGKM0();
        s8v a2[4];
#pragma unroll
        for (int kc = 0; kc < 4; ++kc)
            a2[kc] = *(const s8v*)(hb + l15 * HBS2 + kc * 32 + ch8);

        // layer 2 (swapped), two nt-halves
#pragma unroll
        for (int half = 0; half < 2; ++half) {
            f4v d[4];
#pragma unroll
            for (int j = 0; j < 4; ++j)
                d[j] = *(const f4v*)(bp + 128 + (half * 4 + j) * 16 + quad * 4);
#pragma unroll
            for (int kc = 0; kc < 4; ++kc)
#pragma unroll
                for (int j = 0; j < 4; ++j)
                    d[j] = MFMA(w1f[kc][half * 4 + j], a2[kc], d[j]);
#pragma unroll
            for (int j = 0; j < 4; ++j) {
                u2v pk;
                pk[0] = relu_pk(d[j][0], d[j][1]);
                pk[1] = relu_pk(d[j][2], d[j][3]);
                *(u2v*)(hb + l15 * HBS2 + (half * 4 + j) * 16 + quad * 4) = pk;
            }
        }
        LGKM0();
        s8v a3[4];
#pragma unroll
        for (int kc = 0; kc < 4; ++kc)
            a3[kc] = *(const s8v*)(hb + l15 * HBS2 + kc * 32 + ch8);

        // layer 3 (swapped): quad0 lane l15 holds comps 0..3 of point l15
        f4v o = b2v;
#pragma unroll
        for (int kc = 0; kc < 4; ++kc)
            o = MFMA(w2f[kc], a3[kc], o);

        if (quad == 0) {
            f4v r;
#pragma unroll
            for (int j = 0; j < 4; ++j) r[j] = o[j] > 0.0f ? o[j] : 0.0f;
            const int t = b * 16384 + ci * 512 + nb;   // global tile index
            *(f4v*)(out + (size_t)(t * 16 + l15) * 4) = r;
        }
    }
}

extern "C" void kernel_launch(void* const* d_in, const int* in_sizes, int n_in,
                              void* d_out, int out_size, void* d_ws, size_t ws_size,
                              hipStream_t stream) {
    const float* coords = (const float*)d_in[0];
    const float* tp = (const float*)d_in[1];
    const float* w0 = (const float*)d_in[2];
    const float* b0 = (const float*)d_in[3];
    const float* w1 = (const float*)d_in[4];
    const float* b1 = (const float*)d_in[5];
    const float* w2 = (const float*)d_in[6];
    const float* b2 = (const float*)d_in[7];
    float* out = (float*)d_out;               // FP32 output

    prep_planes_k<<<768, 256, 0, stream>>>(tp);
    prep_weights_k<<<64, 256, 0, stream>>>(w0, b0, w1, b1, w2, b2);
    fused_k<<<2048, 256, 0, stream>>>(coords, out);
}